// Round 5
// baseline (5418.418 us; speedup 1.0000x reference)
//
#include <hip/hip_runtime.h>
#include <hip/hip_bf16.h>
#include <cstdint>

#define T_TOKENS 2048
#define HIDDEN 2048
#define INTER 1408
#define NEXP 16
#define TOPK 4
#define SINTER 2816
#define CAP 768

typedef __attribute__((ext_vector_type(8))) short short8;
typedef __attribute__((ext_vector_type(8))) unsigned short ushort8;
typedef __attribute__((ext_vector_type(4))) float f32x4;

__device__ __forceinline__ float4 ld4f(const float* p) {
  return *reinterpret_cast<const float4*>(p);
}

// bf16 split: v ~= hi + lo, each bf16 (RNE).
__device__ __forceinline__ unsigned short f2bf(float v) {
  unsigned int u = __float_as_uint(v);
  unsigned int r = (u + 0x7FFFu + ((u >> 16) & 1u)) >> 16;
  return (unsigned short)r;
}
__device__ __forceinline__ float bf2f(unsigned short b) {
  return __uint_as_float(((unsigned int)b) << 16);
}
__device__ __forceinline__ void bsplit(float v, unsigned short& h, unsigned short& l) {
  h = f2bf(v);
  l = f2bf(v - bf2f(h));
}

__device__ __forceinline__ void gld16(const void* g, void* l) {
  __builtin_amdgcn_global_load_lds(
      (const __attribute__((address_space(1))) void*)g,
      (__attribute__((address_space(3))) void*)l, 16, 0, 0);
}

// ---------------- router ----------------
__global__ __launch_bounds__(64) void router_kernel(
    const float* __restrict__ x, const float* __restrict__ wg,
    int* __restrict__ topi, float* __restrict__ topw)
{
  const int t = blockIdx.x;
  const int lane = threadIdx.x;
  float acc[NEXP];
#pragma unroll
  for (int e = 0; e < NEXP; ++e) acc[e] = 0.f;
  const float* xr = x + (size_t)t * HIDDEN;
  for (int i = lane; i < HIDDEN; i += 64) {
    float xv = xr[i];
#pragma unroll
    for (int e = 0; e < NEXP; ++e) acc[e] += xv * wg[e * HIDDEN + i];
  }
#pragma unroll
  for (int e = 0; e < NEXP; ++e) {
#pragma unroll
    for (int off = 32; off > 0; off >>= 1)
      acc[e] += __shfl_xor(acc[e], off);
  }
  float m = acc[0];
#pragma unroll
  for (int e = 1; e < NEXP; ++e) m = fmaxf(m, acc[e]);
  float p[NEXP];
  float s = 0.f;
#pragma unroll
  for (int e = 0; e < NEXP; ++e) { p[e] = expf(acc[e] - m); s += p[e]; }
  const float inv = 1.f / s;
#pragma unroll
  for (int e = 0; e < NEXP; ++e) p[e] *= inv;
  if (lane == 0) {
#pragma unroll
    for (int k = 0; k < TOPK; ++k) {
      float best = -1.f; int bi = 0;
#pragma unroll
      for (int e = 0; e < NEXP; ++e)
        if (p[e] > best) { best = p[e]; bi = e; }   // strict >: lowest idx on tie
      topi[t * TOPK + k] = bi;
      topw[t * TOPK + k] = best;  // ROUTED_SCALE = 1.0
      p[bi] = -1.f;
    }
  }
}

// ------------- stable partition -------------
__global__ __launch_bounds__(1024) void partition_kernel(
    const int* __restrict__ topi, float* __restrict__ topw,
    int* __restrict__ rowtok, int* __restrict__ count)
{
  __shared__ int se[T_TOKENS * TOPK];
  for (int i = threadIdx.x; i < T_TOKENS * TOPK; i += 1024) se[i] = topi[i];
  __syncthreads();

  const int wave = threadIdx.x >> 6;
  const int lane = threadIdx.x & 63;
  const uint64_t below = (lane == 0) ? 0ull : ((~0ull) >> (64 - lane));
  int base = 0;
  for (int c = 0; c < T_TOKENS * TOPK; c += 64) {
    int ev = se[c + lane];
    uint64_t mask = __ballot(ev == wave);
    if (ev == wave) {
      int my = base + __popcll(mask & below);
      if (my < CAP) rowtok[wave * CAP + my] = c + lane;
      else          topw[c + lane] = 0.f;
    }
    base += __popcll(mask);
  }
  if (lane == 0) count[wave] = base < CAP ? base : CAP;
}

// ------------- split x -> interleaved hi/lo along K -------------
__global__ __launch_bounds__(256) void split_x_kernel(
    const float* __restrict__ x, unsigned short* __restrict__ xs)
{
  const long i = ((long)blockIdx.x * 256 + threadIdx.x) * 8;
  float4 a = ld4f(x + i), b = ld4f(x + i + 4);
  float v[8] = {a.x, a.y, a.z, a.w, b.x, b.y, b.z, b.w};
  unsigned short o[16];
#pragma unroll
  for (int j = 0; j < 8; ++j) bsplit(v[j], o[2 * j], o[2 * j + 1]);
  *(ushort8*)(xs + 2 * i)     = *(ushort8*)&o[0];
  *(ushort8*)(xs + 2 * i + 8) = *(ushort8*)&o[8];
}

// ------------- transpose + split: W[K][N] -> T[n][2K interleaved] -------------
__global__ __launch_bounds__(256) void tsplit_w_kernel(
    const float* __restrict__ W, unsigned short* __restrict__ T,
    int K, int N)
{
  const long z = blockIdx.z;
  W += z * (long)K * N;
  T += z * (long)K * N * 2;
  const long K2 = 2L * K;
  const int k0 = blockIdx.x * 64, n0 = blockIdx.y * 64;
  __shared__ float tile[64][65];
  const int tr = threadIdx.x >> 4;
  const int tc4 = (threadIdx.x & 15) * 4;
#pragma unroll
  for (int p = 0; p < 4; ++p) {
    int r = p * 16 + tr;
    float4 v = ld4f(W + (long)(k0 + r) * N + n0 + tc4);
    tile[r][tc4] = v.x; tile[r][tc4 + 1] = v.y;
    tile[r][tc4 + 2] = v.z; tile[r][tc4 + 3] = v.w;
  }
  __syncthreads();
  const int wn = threadIdx.x >> 3;          // 0..31
  const int wk = (threadIdx.x & 7) * 8;     // 0..56
#pragma unroll
  for (int p = 0; p < 2; ++p) {
    int n = p * 32 + wn;
    unsigned short o[16];
#pragma unroll
    for (int j = 0; j < 8; ++j) bsplit(tile[wk + j][n], o[2 * j], o[2 * j + 1]);
    long off = (long)(n0 + n) * K2 + 2 * (k0 + wk);
    *(ushort8*)(T + off)     = *(ushort8*)&o[0];
    *(ushort8*)(T + off + 8) = *(ushort8*)&o[8];
  }
}

// ------------- phase-interleaved bf16 MFMA GEMM on K-interleaved planes -------------
// Tile BM x BN (M_REP*32 x N_REP*64), 512 threads = 8 waves (2M x 4N), BK=32.
// 2 sub-phases per K-step; depth-1 counted prefetch via gld16; XOR chunk swizzle
// (pre-swizzled global source, swizzled ds_read) kills the 8-way bank conflict.
template<int M_REP, int N_REP, int EPI>
__global__ __launch_bounds__(512, 4)
void gemm8(const unsigned short* __restrict__ Ag, int ldka,
           const unsigned short* __restrict__ Bg, long bstride, int ldkb,
           int Ncols,
           float* __restrict__ C, unsigned short* __restrict__ H, int ldc,
           const float* __restrict__ G,
           const int* __restrict__ arows_g, int ashift, long aexp,
           const int* __restrict__ crows_g, long cexp,
           const int* __restrict__ cnt, int Mfix, int K2,
           int MT, int NTn)
{
  constexpr int BM = M_REP * 32;
  constexpr int BN = N_REP * 64;
  constexpr int RA = BM / 128;
  constexpr int RB = BN / 128;
  constexpr int HBUF = (BM + BN) * 32;   // ushorts per buffer

  // bijective XCD chunking (all grids % 8 == 0), m-tile fastest
  const int nwg = gridDim.x;
  const int lin = (blockIdx.x & 7) * (nwg >> 3) + (blockIdx.x >> 3);
  const int mt = lin % MT;
  const int rest = lin / MT;
  const int nt = rest % NTn;
  const int e = rest / NTn;

  const int M = cnt ? cnt[e] : Mfix;
  if (mt * BM >= M) return;

  const int tid = threadIdx.x;
  const int l = tid & 63;
  const int w = tid >> 6;
  const int wm = w >> 2;        // 0..1
  const int wn = w & 3;         // 0..3
  const int fr = l & 15;
  const int fc = l >> 4;

  __shared__ __align__(16) unsigned short smem[2 * HBUF];

  const int* arows = arows_g ? arows_g + e * CAP : nullptr;
  const int* crows = crows_g ? crows_g + e * CAP : nullptr;

  // ---- staging setup: lane l -> row (l>>2) of each 128-row round, chunk l&3 ----
  // source chunk pre-swizzled: chunk ^= bits{1,3} of dest LDS row
  const int rb_s = ((l >> 3) & 1) | (((l >> 5) & 1) << 1);
  const int sch = ((l & 3) ^ rb_s) * 8;      // element offset within 32-elem row
  const unsigned short* aptr[RA];
  const unsigned short* bptr[RB];
#pragma unroll
  for (int j = 0; j < RA; ++j) {
    int rloc = j * 128 + w * 16 + (l >> 2);
    int r = mt * BM + rloc; if (r > M - 1) r = M - 1;
    long arow = arows ? (long)(arows[r] >> ashift) : (aexp * e + r);
    aptr[j] = Ag + arow * (long)ldka + sch;
  }
  const unsigned short* Bexp = Bg + (long)e * bstride;
#pragma unroll
  for (int j = 0; j < RB; ++j) {
    int nloc = j * 128 + w * 16 + (l >> 2);
    int n = nt * BN + nloc; if (n > Ncols - 1) n = Ncols - 1;
    bptr[j] = Bexp + (long)n * ldkb + sch;
  }

  // ---- fragment-read swizzle (per-lane constant) ----
  const int rb_r = ((fr >> 1) & 1) | (((fr >> 3) & 1) << 1);
  const int pcoff = ((fc ^ rb_r) * 8);

  f32x4 acc[M_REP][N_REP];
#pragma unroll
  for (int i = 0; i < M_REP; ++i)
#pragma unroll
    for (int j = 0; j < N_REP; ++j) acc[i][j] = (f32x4)0.f;

  const int NT = K2 / 32;

  auto stage = [&](int buf, int t) {
    unsigned short* dA = smem + buf * HBUF;
    unsigned short* dB = smem + buf * HBUF + BM * 32;
#pragma unroll
    for (int j = 0; j < RA; ++j)
      gld16(aptr[j] + (long)t * 32, dA + (j * 128 + w * 16) * 32);
#pragma unroll
    for (int j = 0; j < RB; ++j)
      gld16(bptr[j] + (long)t * 32, dB + (j * 128 + w * 16) * 32);
  };

  stage(0, 0);

  short8 fb[N_REP];
  short8 fa[M_REP / 2];

  for (int t = 0; t < NT; ++t) {
    const int cur = t & 1;
    const unsigned short* sA = smem + cur * HBUF;
    const unsigned short* sB = smem + cur * HBUF + BM * 32;
    // stage(t) was issued a full K-step ago -> covered; all waves' loads landed
    asm volatile("s_waitcnt vmcnt(0)" ::: "memory");
    __builtin_amdgcn_s_barrier();

    // ---- phase 0: prefetch next K-step, B + first A-half, MFMA half ----
    if (t + 1 < NT) stage(cur ^ 1, t + 1);
#pragma unroll
    for (int ni = 0; ni < N_REP; ++ni)
      fb[ni] = *(const short8*)(sB + (wn * N_REP * 16 + ni * 16 + fr) * 32 + pcoff);
#pragma unroll
    for (int mi = 0; mi < M_REP / 2; ++mi)
      fa[mi] = *(const short8*)(sA + (wm * M_REP * 16 + mi * 16 + fr) * 32 + pcoff);
    asm volatile("s_waitcnt lgkmcnt(0)" ::: "memory");
    __builtin_amdgcn_sched_barrier(0);
    __builtin_amdgcn_s_setprio(1);
#pragma unroll
    for (int mi = 0; mi < M_REP / 2; ++mi)
#pragma unroll
      for (int ni = 0; ni < N_REP; ++ni)
        acc[mi][ni] = __builtin_amdgcn_mfma_f32_16x16x32_bf16(fa[mi], fb[ni], acc[mi][ni], 0, 0, 0);
    __builtin_amdgcn_s_setprio(0);
    __builtin_amdgcn_s_barrier();

    // ---- phase 1: second A-half, MFMA half ----
#pragma unroll
    for (int mi = 0; mi < M_REP / 2; ++mi)
      fa[mi] = *(const short8*)(sA + (wm * M_REP * 16 + (M_REP / 2 + mi) * 16 + fr) * 32 + pcoff);
    asm volatile("s_waitcnt lgkmcnt(0)" ::: "memory");
    __builtin_amdgcn_sched_barrier(0);
    __builtin_amdgcn_s_setprio(1);
#pragma unroll
    for (int mi = 0; mi < M_REP / 2; ++mi)
#pragma unroll
      for (int ni = 0; ni < N_REP; ++ni)
        acc[M_REP / 2 + mi][ni] =
            __builtin_amdgcn_mfma_f32_16x16x32_bf16(fa[mi], fb[ni], acc[M_REP / 2 + mi][ni], 0, 0, 0);
    __builtin_amdgcn_s_setprio(0);
  }

  // ---- epilogue: C/D layout col=lane&15, row=(lane>>4)*4+rr ----
#pragma unroll
  for (int mi = 0; mi < M_REP; ++mi)
#pragma unroll
    for (int rr = 0; rr < 4; ++rr) {
      const int r = mt * BM + wm * M_REP * 16 + mi * 16 + fc * 4 + rr;
      if (r >= M) continue;
      const long crow = crows ? (long)crows[r] : (cexp * e + r);
#pragma unroll
      for (int ni = 0; ni < N_REP; ++ni) {
        const int col = nt * BN + wn * N_REP * 16 + ni * 16 + fr;
        if (col >= Ncols) continue;
        const float v = acc[mi][ni][rr];
        if constexpr (EPI == 1) {
          const long goff = crow * (long)ldc + col;
          const float g = G[goff];
          const float h = v * (g / (1.f + __expf(-g)));   // silu(g)*u
          unsigned short hh, hl;
          bsplit(h, hh, hl);
          *(unsigned int*)(H + crow * (long)(2 * ldc) + 2 * col) =
              (unsigned int)hh | ((unsigned int)hl << 16);
        } else {
          C[crow * (long)ldc + col] = v;
        }
      }
    }
}

// ------------- combine -------------
__global__ __launch_bounds__(256) void combine_kernel(
    const float* __restrict__ o_slot, const float* __restrict__ topw,
    float* __restrict__ out)
{
  const int t = blockIdx.x;
  float w[TOPK];
#pragma unroll
  for (int k = 0; k < TOPK; ++k) w[k] = topw[t * TOPK + k];
  float* orow = out + (size_t)t * HIDDEN;
  for (int c = threadIdx.x * 4; c < HIDDEN; c += 256 * 4) {
    float4 acc = *reinterpret_cast<float4*>(orow + c);
#pragma unroll
    for (int k = 0; k < TOPK; ++k) {
      if (w[k] != 0.f) {
        float4 v = ld4f(o_slot + ((size_t)(t * TOPK + k)) * HIDDEN + c);
        acc.x += w[k] * v.x; acc.y += w[k] * v.y;
        acc.z += w[k] * v.z; acc.w += w[k] * v.w;
      }
    }
    *reinterpret_cast<float4*>(orow + c) = acc;
  }
}

extern "C" void kernel_launch(void* const* d_in, const int* in_sizes, int n_in,
                              void* d_out, int out_size, void* d_ws, size_t ws_size,
                              hipStream_t stream)
{
  const float* x   = (const float*)d_in[0];
  const float* wg  = (const float*)d_in[1];
  const float* w1  = (const float*)d_in[2];
  const float* w3  = (const float*)d_in[3];
  const float* w2  = (const float*)d_in[4];
  const float* ws1 = (const float*)d_in[5];
  const float* ws3 = (const float*)d_in[6];
  const float* ws2 = (const float*)d_in[7];
  float* out = (float*)d_out;

  char* w = (char*)d_ws;
  int*   topi   = (int*)w;   w += (size_t)T_TOKENS * TOPK * 4;
  float* topw   = (float*)w; w += (size_t)T_TOKENS * TOPK * 4;
  int*   rowtok = (int*)w;   w += (size_t)NEXP * CAP * 4;
  int*   count  = (int*)w;   w += 256;
  uintptr_t a = (uintptr_t)w; a = (a + 255) & ~(uintptr_t)255; w = (char*)a;

  // interleaved-plane buffers (ushort counts)
  unsigned short* xs = (unsigned short*)w; w += (size_t)T_TOKENS * 2 * HIDDEN * 2;       // 16.8 MB
  unsigned short* wS = (unsigned short*)w; w += (size_t)2 * HIDDEN * SINTER * 2;         // 23.1 MB (rotated)
  unsigned short* wR = (unsigned short*)w; w += (size_t)NEXP * 2 * HIDDEN * INTER * 2;   // 184.5 MB (rotated)
  unsigned short* hs = (unsigned short*)w; w += (size_t)T_TOKENS * 2 * SINTER * 2;       // 23.1 MB
  unsigned short* hr = (unsigned short*)w; w += (size_t)NEXP * CAP * 2 * INTER * 2;      // 69.2 MB
  float* gbuf = (float*)w;   w += (size_t)NEXP * CAP * INTER * 4;                        // 69.2 MB
  float* o_slot = gbuf;      // o_slot [8192][2048] fp32 reuses g region after K2

  router_kernel<<<T_TOKENS, 64, 0, stream>>>(x, wg, topi, topw);
  partition_kernel<<<1, 1024, 0, stream>>>(topi, topw, rowtok, count);
  split_x_kernel<<<(T_TOKENS * HIDDEN) / (256 * 8), 256, 0, stream>>>(x, xs);

  // ---- shared up: g_s = x @ ws1 ----
  tsplit_w_kernel<<<dim3(HIDDEN / 64, SINTER / 64, 1), 256, 0, stream>>>(ws1, wS, HIDDEN, SINTER);
  gemm8<4, 2, 0><<<(T_TOKENS / 128) * (SINTER / 128), 512, 0, stream>>>(
      xs, 2 * HIDDEN, wS, 0L, 2 * HIDDEN, SINTER,
      gbuf, nullptr, SINTER, nullptr,
      nullptr, 0, 0L, nullptr, 0L,
      nullptr, T_TOKENS, 2 * HIDDEN, T_TOKENS / 128, SINTER / 128);
  // ---- shared gate: hs = silu(g_s) * (x @ ws3), split-interleaved ----
  tsplit_w_kernel<<<dim3(HIDDEN / 64, SINTER / 64, 1), 256, 0, stream>>>(ws3, wS, HIDDEN, SINTER);
  gemm8<4, 2, 1><<<(T_TOKENS / 128) * (SINTER / 128), 512, 0, stream>>>(
      xs, 2 * HIDDEN, wS, 0L, 2 * HIDDEN, SINTER,
      nullptr, hs, SINTER, gbuf,
      nullptr, 0, 0L, nullptr, 0L,
      nullptr, T_TOKENS, 2 * HIDDEN, T_TOKENS / 128, SINTER / 128);

  // ---- routed up: g_r = gather(x) @ w1[e] ----
  tsplit_w_kernel<<<dim3(HIDDEN / 64, INTER / 64, NEXP), 256, 0, stream>>>(w1, wR, HIDDEN, INTER);
  gemm8<8, 4, 0><<<(CAP / 256) * 6 * NEXP, 512, 0, stream>>>(
      xs, 2 * HIDDEN, wR, (long)INTER * 2 * HIDDEN, 2 * HIDDEN, INTER,
      gbuf, nullptr, INTER, nullptr,
      rowtok, 2, 0L, nullptr, (long)CAP,
      count, 0, 2 * HIDDEN, CAP / 256, 6);
  // ---- routed gate: hr = silu(g_r) * (gather(x) @ w3[e]), split-interleaved ----
  tsplit_w_kernel<<<dim3(HIDDEN / 64, INTER / 64, NEXP), 256, 0, stream>>>(w3, wR, HIDDEN, INTER);
  gemm8<8, 4, 1><<<(CAP / 256) * 6 * NEXP, 512, 0, stream>>>(
      xs, 2 * HIDDEN, wR, (long)INTER * 2 * HIDDEN, 2 * HIDDEN, INTER,
      nullptr, hr, INTER, gbuf,
      rowtok, 2, 0L, nullptr, (long)CAP,
      count, 0, 2 * HIDDEN, CAP / 256, 6);

  // ---- shared down: out = hs @ ws2 ----
  tsplit_w_kernel<<<dim3(SINTER / 64, HIDDEN / 64, 1), 256, 0, stream>>>(ws2, wS, SINTER, HIDDEN);
  gemm8<4, 2, 0><<<(T_TOKENS / 128) * (HIDDEN / 128), 512, 0, stream>>>(
      hs, 2 * SINTER, wS, 0L, 2 * SINTER, HIDDEN,
      out, nullptr, HIDDEN, nullptr,
      nullptr, 0, 0L, nullptr, 0L,
      nullptr, T_TOKENS, 2 * SINTER, T_TOKENS / 128, HIDDEN / 128);

  // ---- routed down: o_slot = hr @ w2[e], scattered to slot rows ----
  tsplit_w_kernel<<<dim3(INTER / 64, HIDDEN / 64, NEXP), 256, 0, stream>>>(w2, wR, INTER, HIDDEN);
  gemm8<8, 4, 0><<<(CAP / 256) * (HIDDEN / 256) * NEXP, 512, 0, stream>>>(
      hr, 2 * INTER, wR, (long)HIDDEN * 2 * INTER, 2 * INTER, HIDDEN,
      o_slot, nullptr, HIDDEN, nullptr,
      nullptr, 0, (long)CAP, rowtok, 0L,
      count, 0, 2 * INTER, CAP / 256, HIDDEN / 256);

  combine_kernel<<<T_TOKENS, 256, 0, stream>>>(o_slot, topw, out);
}

// Round 6
// 691.592 us; speedup vs baseline: 7.8347x; 7.8347x over previous
//
#include <hip/hip_runtime.h>
#include <hip/hip_bf16.h>
#include <cstdint>

#define T_TOKENS 2048
#define HIDDEN 2048
#define INTER 1408
#define NEXP 16
#define TOPK 4
#define SINTER 2816
#define CAP 768
#define BK 32

typedef __attribute__((ext_vector_type(8))) short short8;
typedef __attribute__((ext_vector_type(8))) unsigned short ushort8;
typedef __attribute__((ext_vector_type(4))) float f32x4;

__device__ __forceinline__ float4 ld4f(const float* p) {
  return *reinterpret_cast<const float4*>(p);
}

__device__ __forceinline__ unsigned short f2bf(float v) {
  unsigned int u = __float_as_uint(v);
  unsigned int r = (u + 0x7FFFu + ((u >> 16) & 1u)) >> 16;  // RNE
  return (unsigned short)r;
}

__device__ __forceinline__ void gld16(const void* g, void* l) {
  __builtin_amdgcn_global_load_lds(
      (const __attribute__((address_space(1))) void*)g,
      (__attribute__((address_space(3))) void*)l, 16, 0, 0);
}

// ---------------- router: logits -> softmax -> top4 ----------------
__global__ __launch_bounds__(64) void router_kernel(
    const float* __restrict__ x, const float* __restrict__ wg,
    int* __restrict__ topi, float* __restrict__ topw)
{
  const int t = blockIdx.x;
  const int lane = threadIdx.x;
  float acc[NEXP];
#pragma unroll
  for (int e = 0; e < NEXP; ++e) acc[e] = 0.f;
  const float* xr = x + (size_t)t * HIDDEN;
  for (int i = lane; i < HIDDEN; i += 64) {
    float xv = xr[i];
#pragma unroll
    for (int e = 0; e < NEXP; ++e) acc[e] += xv * wg[e * HIDDEN + i];
  }
#pragma unroll
  for (int e = 0; e < NEXP; ++e) {
#pragma unroll
    for (int off = 32; off > 0; off >>= 1)
      acc[e] += __shfl_xor(acc[e], off);
  }
  float m = acc[0];
#pragma unroll
  for (int e = 1; e < NEXP; ++e) m = fmaxf(m, acc[e]);
  float p[NEXP];
  float s = 0.f;
#pragma unroll
  for (int e = 0; e < NEXP; ++e) { p[e] = expf(acc[e] - m); s += p[e]; }
  const float inv = 1.f / s;
#pragma unroll
  for (int e = 0; e < NEXP; ++e) p[e] *= inv;
  if (lane == 0) {
#pragma unroll
    for (int k = 0; k < TOPK; ++k) {
      float best = -1.f; int bi = 0;
#pragma unroll
      for (int e = 0; e < NEXP; ++e)
        if (p[e] > best) { best = p[e]; bi = e; }   // strict >: lowest idx on tie
      topi[t * TOPK + k] = bi;
      topw[t * TOPK + k] = best;  // ROUTED_SCALE = 1.0
      p[bi] = -1.f;
    }
  }
}

// ------------- stable partition: slot -> (expert,pos), exact cumsum order -------------
__global__ __launch_bounds__(1024) void partition_kernel(
    const int* __restrict__ topi, float* __restrict__ topw,
    int* __restrict__ rowtok, int* __restrict__ count)
{
  __shared__ int se[T_TOKENS * TOPK];
  for (int i = threadIdx.x; i < T_TOKENS * TOPK; i += 1024) se[i] = topi[i];
  __syncthreads();

  const int wave = threadIdx.x >> 6;
  const int lane = threadIdx.x & 63;
  const uint64_t below = (lane == 0) ? 0ull : ((~0ull) >> (64 - lane));
  int base = 0;
  for (int c = 0; c < T_TOKENS * TOPK; c += 64) {
    int ev = se[c + lane];
    uint64_t mask = __ballot(ev == wave);
    if (ev == wave) {
      int my = base + __popcll(mask & below);
      if (my < CAP) rowtok[wave * CAP + my] = c + lane;
      else          topw[c + lane] = 0.f;
    }
    base += __popcll(mask);
  }
  if (lane == 0) count[wave] = base < CAP ? base : CAP;
}

// ------------- convert x -> bf16 -------------
__global__ __launch_bounds__(256) void cvt_x_kernel(
    const float* __restrict__ x, unsigned short* __restrict__ xb)
{
  const long i = ((long)blockIdx.x * 256 + threadIdx.x) * 8;
  float4 a = ld4f(x + i), b = ld4f(x + i + 4);
  float v[8] = {a.x, a.y, a.z, a.w, b.x, b.y, b.z, b.w};
  unsigned short o[8];
#pragma unroll
  for (int j = 0; j < 8; ++j) o[j] = f2bf(v[j]);
  *(ushort8*)(xb + i) = *(ushort8*)&o[0];
}

// ------------- transpose + convert: W[K][N] -> T[N][K] bf16 (per expert z) -------------
__global__ __launch_bounds__(256) void tcvt_w_kernel(
    const float* __restrict__ W, unsigned short* __restrict__ T,
    int K, int N)
{
  const long z = blockIdx.z;
  W += z * (long)K * N;
  T += z * (long)K * N;
  const int k0 = blockIdx.x * 64, n0 = blockIdx.y * 64;
  __shared__ float tile[64][65];
  const int tr = threadIdx.x >> 4;
  const int tc4 = (threadIdx.x & 15) * 4;
#pragma unroll
  for (int p = 0; p < 4; ++p) {
    int r = p * 16 + tr;
    float4 v = ld4f(W + (long)(k0 + r) * N + n0 + tc4);
    tile[r][tc4] = v.x; tile[r][tc4 + 1] = v.y;
    tile[r][tc4 + 2] = v.z; tile[r][tc4 + 3] = v.w;
  }
  __syncthreads();
  const int wn = threadIdx.x >> 3;          // 0..31
  const int wk = (threadIdx.x & 7) * 8;     // 0..56
#pragma unroll
  for (int p = 0; p < 2; ++p) {
    int n = p * 32 + wn;
    unsigned short o[8];
#pragma unroll
    for (int j = 0; j < 8; ++j) o[j] = f2bf(tile[wk + j][n]);
    *(ushort8*)(T + (long)(n0 + n) * K + k0 + wk) = *(ushort8*)&o[0];
  }
}

// ------------- plain bf16 MFMA GEMM, gload_lds staged, swizzled LDS -------------
// 128x128 tile, BK=32, 256 threads = 4 waves (2x2), wave tile 64x64, dbuf LDS.
// XOR chunk swizzle: physical chunk = logical chunk ^ (row bits{1,3}) -> 0 conflicts
// (verified R5). Source chunk pre-swizzled so gload_lds dest stays linear (rule #21).
// 1D grid, bijective XCD chunking (nwg%8==0), m-tile fastest.
template<int EPI>   // 0: C fp32; 1: read G fp32, write silu(G)*acc as bf16 into H
__global__ __launch_bounds__(256, 2)
void gemm_bf(const unsigned short* __restrict__ Ag, int ldka,
             const unsigned short* __restrict__ Bg, long bstride,
             float* __restrict__ C, unsigned short* __restrict__ H, int ldc,
             const float* __restrict__ G,
             const int* __restrict__ arows_g, int ashift, long aexp,
             const int* __restrict__ crows_g, long cexp,
             const int* __restrict__ cnt, int Mfix, int K,
             int MT, int NTn)
{
  const int nwg = gridDim.x;
  const int lin = (blockIdx.x & 7) * (nwg >> 3) + (blockIdx.x >> 3);
  const int mt = lin % MT;
  const int rest = lin / MT;
  const int nt = rest % NTn;
  const int e = rest / NTn;

  const int M = cnt ? cnt[e] : Mfix;
  if (mt * 128 >= M) return;
  const int n0 = nt * 128;

  const int tid = threadIdx.x;
  const int l = tid & 63;
  const int w = tid >> 6;
  const int wm = w >> 1;        // 0..1
  const int wn = w & 1;         // 0..1
  const int fr = l & 15;
  const int fc = l >> 4;

  const int* arows = arows_g ? arows_g + e * CAP : nullptr;
  const int* crows = crows_g ? crows_g + e * CAP : nullptr;
  const unsigned short* Bexp = Bg + (long)e * bstride;

  __shared__ __align__(16) unsigned short sA[2][128 * BK];
  __shared__ __align__(16) unsigned short sB[2][128 * BK];

  // staging: round j covers rows j*64 + w*16 .. +15; lane l -> row +(l>>2), chunk l&3.
  // pre-swizzle source chunk by dest-row bits {1,3}:
  const int rb_s = ((l >> 3) & 1) | (((l >> 5) & 1) << 1);
  const int sch = ((l & 3) ^ rb_s) * 8;      // element offset within 32-elem row
  long aoff[2], boff[2];
#pragma unroll
  for (int j = 0; j < 2; ++j) {
    const int rloc = j * 64 + w * 16 + (l >> 2);
    int r = mt * 128 + rloc;
    if (r > M - 1) r = M - 1;
    const long arow = arows ? (long)(arows[r] >> ashift) : (aexp * e + r);
    aoff[j] = arow * (long)ldka + sch;
    boff[j] = (long)(n0 + rloc) * K + sch;
  }

  // fragment-read swizzle (per-lane constant): physical chunk = fc ^ bits{1,3}(fr)
  const int rb_r = ((fr >> 1) & 1) | (((fr >> 3) & 1) << 1);
  const int pcoff = (fc ^ rb_r) * 8;

  f32x4 acc[4][4];
#pragma unroll
  for (int i = 0; i < 4; ++i)
#pragma unroll
    for (int j = 0; j < 4; ++j) acc[i][j] = (f32x4)0.f;

  const int NT = K / BK;

  auto stage = [&](int buf, int kt) {
#pragma unroll
    for (int j = 0; j < 2; ++j) {
      gld16(Ag + aoff[j] + kt, &sA[buf][(j * 64 + w * 16) * BK]);
      gld16(Bexp + boff[j] + kt, &sB[buf][(j * 64 + w * 16) * BK]);
    }
  };

  stage(0, 0);
  asm volatile("s_waitcnt vmcnt(0)" ::: "memory");
  __syncthreads();

  for (int t = 0; t < NT; ++t) {
    const int cur = t & 1;
    if (t + 1 < NT) stage(cur ^ 1, (t + 1) * BK);

    short8 fa[4], fb[4];
#pragma unroll
    for (int mi = 0; mi < 4; ++mi)
      fa[mi] = *(const short8*)&sA[cur][(wm * 64 + mi * 16 + fr) * BK + pcoff];
#pragma unroll
    for (int ni = 0; ni < 4; ++ni)
      fb[ni] = *(const short8*)&sB[cur][(wn * 64 + ni * 16 + fr) * BK + pcoff];
#pragma unroll
    for (int mi = 0; mi < 4; ++mi)
#pragma unroll
      for (int ni = 0; ni < 4; ++ni)
        acc[mi][ni] = __builtin_amdgcn_mfma_f32_16x16x32_bf16(fa[mi], fb[ni], acc[mi][ni], 0, 0, 0);

    asm volatile("s_waitcnt vmcnt(0)" ::: "memory");
    __syncthreads();
  }

  // epilogue: C/D layout col=lane&15, row=(lane>>4)*4+rr
#pragma unroll
  for (int mi = 0; mi < 4; ++mi)
#pragma unroll
    for (int rr = 0; rr < 4; ++rr) {
      const int r = mt * 128 + wm * 64 + mi * 16 + fc * 4 + rr;
      if (r >= M) continue;
      const long crow = crows ? (long)crows[r] : (cexp * e + r);
#pragma unroll
      for (int ni = 0; ni < 4; ++ni) {
        const int col = n0 + wn * 64 + ni * 16 + fr;
        const long off = crow * (long)ldc + col;
        const float v = acc[mi][ni][rr];
        if constexpr (EPI == 1) {
          const float g = G[off];
          const float h = v * (g / (1.f + __expf(-g)));   // silu(g)*u
          H[off] = f2bf(h);
        } else {
          C[off] = v;
        }
      }
    }
}

// ------------- combine: out[t] += sum_k w_k * o_slot[t*4+k] -------------
__global__ __launch_bounds__(256) void combine_kernel(
    const float* __restrict__ o_slot, const float* __restrict__ topw,
    float* __restrict__ out)
{
  const int t = blockIdx.x;
  float w[TOPK];
#pragma unroll
  for (int k = 0; k < TOPK; ++k) w[k] = topw[t * TOPK + k];
  float* orow = out + (size_t)t * HIDDEN;
  for (int c = threadIdx.x * 4; c < HIDDEN; c += 256 * 4) {
    float4 acc = *reinterpret_cast<float4*>(orow + c);
#pragma unroll
    for (int k = 0; k < TOPK; ++k) {
      if (w[k] != 0.f) {
        float4 v = ld4f(o_slot + ((size_t)(t * TOPK + k)) * HIDDEN + c);
        acc.x += w[k] * v.x; acc.y += w[k] * v.y;
        acc.z += w[k] * v.z; acc.w += w[k] * v.w;
      }
    }
    *reinterpret_cast<float4*>(orow + c) = acc;
  }
}

extern "C" void kernel_launch(void* const* d_in, const int* in_sizes, int n_in,
                              void* d_out, int out_size, void* d_ws, size_t ws_size,
                              hipStream_t stream)
{
  const float* x   = (const float*)d_in[0];
  const float* wg  = (const float*)d_in[1];
  const float* w1  = (const float*)d_in[2];
  const float* w3  = (const float*)d_in[3];
  const float* w2  = (const float*)d_in[4];
  const float* ws1 = (const float*)d_in[5];
  const float* ws3 = (const float*)d_in[6];
  const float* ws2 = (const float*)d_in[7];
  float* out = (float*)d_out;

  char* w = (char*)d_ws;
  int*   topi   = (int*)w;   w += (size_t)T_TOKENS * TOPK * 4;
  float* topw   = (float*)w; w += (size_t)T_TOKENS * TOPK * 4;
  int*   rowtok = (int*)w;   w += (size_t)NEXP * CAP * 4;
  int*   count  = (int*)w;   w += 256;
  uintptr_t a = (uintptr_t)w; a = (a + 255) & ~(uintptr_t)255; w = (char*)a;

  const size_t XSZ  = (size_t)T_TOKENS * HIDDEN;          // 4.19M
  const size_t WSSZ = (size_t)HIDDEN * SINTER;            // 5.77M
  const size_t WRSZ = (size_t)NEXP * HIDDEN * INTER;      // 46.1M
  const size_t HSSZ = (size_t)T_TOKENS * SINTER;          // 5.77M
  const size_t HRSZ = (size_t)NEXP * CAP * INTER;         // 17.3M

  unsigned short* xb = (unsigned short*)w; w += XSZ * 2;    // 8.4 MB
  unsigned short* wS = (unsigned short*)w; w += WSSZ * 2;   // 11.5 MB (rotated ws1T/ws3T/ws2T)
  unsigned short* wR = (unsigned short*)w; w += WRSZ * 2;   // 92.3 MB (rotated w1T/w3T/w2T)
  unsigned short* hs = (unsigned short*)w; w += HSSZ * 2;   // 11.5 MB
  unsigned short* hr = (unsigned short*)w; w += HRSZ * 2;   // 34.6 MB
  float* gbuf = (float*)w;   w += (size_t)NEXP * CAP * INTER * 4;  // 69.2 MB
  float* o_slot = gbuf;      // o_slot [8192][2048] fp32 reuses g region

  router_kernel<<<T_TOKENS, 64, 0, stream>>>(x, wg, topi, topw);
  partition_kernel<<<1, 1024, 0, stream>>>(topi, topw, rowtok, count);
  cvt_x_kernel<<<(int)(XSZ / (256 * 8)), 256, 0, stream>>>(x, xb);

  // ---- shared up: g_s = x @ ws1 ----
  tcvt_w_kernel<<<dim3(HIDDEN / 64, SINTER / 64, 1), 256, 0, stream>>>(ws1, wS, HIDDEN, SINTER);
  gemm_bf<0><<<(T_TOKENS / 128) * (SINTER / 128), 256, 0, stream>>>(
      xb, HIDDEN, wS, 0L, gbuf, nullptr, SINTER, nullptr,
      nullptr, 0, 0L, nullptr, 0L,
      nullptr, T_TOKENS, HIDDEN, T_TOKENS / 128, SINTER / 128);
  // ---- shared gate: hs = silu(g_s) * (x @ ws3) ----
  tcvt_w_kernel<<<dim3(HIDDEN / 64, SINTER / 64, 1), 256, 0, stream>>>(ws3, wS, HIDDEN, SINTER);
  gemm_bf<1><<<(T_TOKENS / 128) * (SINTER / 128), 256, 0, stream>>>(
      xb, HIDDEN, wS, 0L, nullptr, hs, SINTER, gbuf,
      nullptr, 0, 0L, nullptr, 0L,
      nullptr, T_TOKENS, HIDDEN, T_TOKENS / 128, SINTER / 128);

  // ---- routed up: g_r = gather(x) @ w1[e] ----
  tcvt_w_kernel<<<dim3(HIDDEN / 64, INTER / 64, NEXP), 256, 0, stream>>>(w1, wR, HIDDEN, INTER);
  gemm_bf<0><<<(CAP / 128) * (INTER / 128) * NEXP, 256, 0, stream>>>(
      xb, HIDDEN, wR, (long)INTER * HIDDEN, gbuf, nullptr, INTER, nullptr,
      rowtok, 2, 0L, nullptr, (long)CAP,
      count, 0, HIDDEN, CAP / 128, INTER / 128);
  // ---- routed gate: hr = silu(g_r) * (gather(x) @ w3[e]) ----
  tcvt_w_kernel<<<dim3(HIDDEN / 64, INTER / 64, NEXP), 256, 0, stream>>>(w3, wR, HIDDEN, INTER);
  gemm_bf<1><<<(CAP / 128) * (INTER / 128) * NEXP, 256, 0, stream>>>(
      xb, HIDDEN, wR, (long)INTER * HIDDEN, nullptr, hr, INTER, gbuf,
      rowtok, 2, 0L, nullptr, (long)CAP,
      count, 0, HIDDEN, CAP / 128, INTER / 128);

  // ---- shared down: out = hs @ ws2 ----
  tcvt_w_kernel<<<dim3(SINTER / 64, HIDDEN / 64, 1), 256, 0, stream>>>(ws2, wS, SINTER, HIDDEN);
  gemm_bf<0><<<(T_TOKENS / 128) * (HIDDEN / 128), 256, 0, stream>>>(
      hs, SINTER, wS, 0L, out, nullptr, HIDDEN, nullptr,
      nullptr, 0, 0L, nullptr, 0L,
      nullptr, T_TOKENS, SINTER, T_TOKENS / 128, HIDDEN / 128);

  // ---- routed down: o_slot = hr @ w2[e], scattered to slot rows ----
  tcvt_w_kernel<<<dim3(INTER / 64, HIDDEN / 64, NEXP), 256, 0, stream>>>(w2, wR, INTER, HIDDEN);
  gemm_bf<0><<<(CAP / 128) * (HIDDEN / 128) * NEXP, 256, 0, stream>>>(
      hr, INTER, wR, (long)HIDDEN * INTER, o_slot, nullptr, HIDDEN, nullptr,
      nullptr, 0, (long)CAP, rowtok, 0L,
      count, 0, INTER, CAP / 128, HIDDEN / 128);

  combine_kernel<<<T_TOKENS, 256, 0, stream>>>(o_slot, topw, out);
}

// Round 8
// 635.761 us; speedup vs baseline: 8.5227x; 1.0878x over previous
//
#include <hip/hip_runtime.h>
#include <hip/hip_bf16.h>
#include <cstdint>

#define T_TOKENS 2048
#define HIDDEN 2048
#define INTER 1408
#define NEXP 16
#define TOPK 4
#define SINTER 2816
#define CAP 768
#define BK 32

typedef __attribute__((ext_vector_type(8))) short short8;
typedef __attribute__((ext_vector_type(8))) unsigned short ushort8;
typedef __attribute__((ext_vector_type(4))) float f32x4;

__device__ __forceinline__ float4 ld4f(const float* p) {
  return *reinterpret_cast<const float4*>(p);
}

__device__ __forceinline__ unsigned short f2bf(float v) {
  unsigned int u = __float_as_uint(v);
  unsigned int r = (u + 0x7FFFu + ((u >> 16) & 1u)) >> 16;  // RNE
  return (unsigned short)r;
}

__device__ __forceinline__ void gld16(const void* g, void* l) {
  __builtin_amdgcn_global_load_lds(
      (const __attribute__((address_space(1))) void*)g,
      (__attribute__((address_space(3))) void*)l, 16, 0, 0);
}

// ---------------- router: logits -> softmax -> top4 ----------------
__global__ __launch_bounds__(64) void router_kernel(
    const float* __restrict__ x, const float* __restrict__ wg,
    int* __restrict__ topi, float* __restrict__ topw)
{
  const int t = blockIdx.x;
  const int lane = threadIdx.x;
  float acc[NEXP];
#pragma unroll
  for (int e = 0; e < NEXP; ++e) acc[e] = 0.f;
  const float* xr = x + (size_t)t * HIDDEN;
  for (int i = lane; i < HIDDEN; i += 64) {
    float xv = xr[i];
#pragma unroll
    for (int e = 0; e < NEXP; ++e) acc[e] += xv * wg[e * HIDDEN + i];
  }
#pragma unroll
  for (int e = 0; e < NEXP; ++e) {
#pragma unroll
    for (int off = 32; off > 0; off >>= 1)
      acc[e] += __shfl_xor(acc[e], off);
  }
  float m = acc[0];
#pragma unroll
  for (int e = 1; e < NEXP; ++e) m = fmaxf(m, acc[e]);
  float p[NEXP];
  float s = 0.f;
#pragma unroll
  for (int e = 0; e < NEXP; ++e) { p[e] = expf(acc[e] - m); s += p[e]; }
  const float inv = 1.f / s;
#pragma unroll
  for (int e = 0; e < NEXP; ++e) p[e] *= inv;
  if (lane == 0) {
#pragma unroll
    for (int k = 0; k < TOPK; ++k) {
      float best = -1.f; int bi = 0;
#pragma unroll
      for (int e = 0; e < NEXP; ++e)
        if (p[e] > best) { best = p[e]; bi = e; }   // strict >: lowest idx on tie
      topi[t * TOPK + k] = bi;
      topw[t * TOPK + k] = best;  // ROUTED_SCALE = 1.0
      p[bi] = -1.f;
    }
  }
}

// ------------- stable partition: slot -> (expert,pos), exact cumsum order -------------
__global__ __launch_bounds__(1024) void partition_kernel(
    const int* __restrict__ topi, float* __restrict__ topw,
    int* __restrict__ rowtok, int* __restrict__ count)
{
  __shared__ int se[T_TOKENS * TOPK];
  for (int i = threadIdx.x; i < T_TOKENS * TOPK; i += 1024) se[i] = topi[i];
  __syncthreads();

  const int wave = threadIdx.x >> 6;
  const int lane = threadIdx.x & 63;
  const uint64_t below = (lane == 0) ? 0ull : ((~0ull) >> (64 - lane));
  int base = 0;
  for (int c = 0; c < T_TOKENS * TOPK; c += 64) {
    int ev = se[c + lane];
    uint64_t mask = __ballot(ev == wave);
    if (ev == wave) {
      int my = base + __popcll(mask & below);
      if (my < CAP) rowtok[wave * CAP + my] = c + lane;
      else          topw[c + lane] = 0.f;
    }
    base += __popcll(mask);
  }
  if (lane == 0) count[wave] = base < CAP ? base : CAP;
}

// ------------- convert x -> bf16 -------------
__global__ __launch_bounds__(256) void cvt_x_kernel(
    const float* __restrict__ x, unsigned short* __restrict__ xb)
{
  const long i = ((long)blockIdx.x * 256 + threadIdx.x) * 8;
  float4 a = ld4f(x + i), b = ld4f(x + i + 4);
  float v[8] = {a.x, a.y, a.z, a.w, b.x, b.y, b.z, b.w};
  unsigned short o[8];
#pragma unroll
  for (int j = 0; j < 8; ++j) o[j] = f2bf(v[j]);
  *(ushort8*)(xb + i) = *(ushort8*)&o[0];
}

// ------------- transpose + convert: W[K][N] -> T[prow(N)][K] bf16 (per expert z) ------
// prow(n) = ((n>>4)*mul + which)*16 + (n&15): mul=1,which=0 plain transpose;
// mul=2,which={0,1} interleaves two weights in alternating 16-column blocks.
__global__ __launch_bounds__(256) void tcvt_w_kernel(
    const float* __restrict__ W, unsigned short* __restrict__ T,
    int K, int N, long tz, int mul, int which)
{
  const long z = blockIdx.z;
  W += z * (long)K * N;
  T += z * tz;
  const int k0 = blockIdx.x * 64, n0 = blockIdx.y * 64;
  __shared__ float tile[64][65];
  const int tr = threadIdx.x >> 4;
  const int tc4 = (threadIdx.x & 15) * 4;
#pragma unroll
  for (int p = 0; p < 4; ++p) {
    int r = p * 16 + tr;
    float4 v = ld4f(W + (long)(k0 + r) * N + n0 + tc4);
    tile[r][tc4] = v.x; tile[r][tc4 + 1] = v.y;
    tile[r][tc4 + 2] = v.z; tile[r][tc4 + 3] = v.w;
  }
  __syncthreads();
  const int wn = threadIdx.x >> 3;          // 0..31
  const int wk = (threadIdx.x & 7) * 8;     // 0..56
#pragma unroll
  for (int p = 0; p < 2; ++p) {
    int n = p * 32 + wn;
    unsigned short o[8];
#pragma unroll
    for (int j = 0; j < 8; ++j) o[j] = f2bf(tile[wk + j][n]);
    const int gn = n0 + n;
    const long prow = ((long)(gn >> 4) * mul + which) * 16 + (gn & 15);
    *(ushort8*)(T + prow * K + k0 + wk) = *(ushort8*)&o[0];
  }
}

// ------------- bf16 MFMA GEMM, depth-2 counted prefetch, swizzled LDS -------------
// 128x128 tile, BK=32, 256 threads = 4 waves (2x2), wave tile 64x64, 3-buffer LDS.
// Pipeline: prologue stages tiles 0,1; iter t: vmcnt(4) [stage(t) done, issued 2
// iters ago] -> barrier -> stage(t+2) -> ds_read buf[t%3] -> MFMA. One barrier/iter.
// XOR chunk swizzle (verified R5/R6): 0 bank conflicts; gload_lds dest linear.
// EPI=0: C fp32 at physical cols. EPI=2: fused SwiGLU on 16-col-interleaved B
// (even frag = gate, odd frag = up, same lane/row) -> bf16 H at logical cols.
template<int EPI>
__global__ __launch_bounds__(256, 2)
void gemm_bf(const unsigned short* __restrict__ Ag, int ldka,
             const unsigned short* __restrict__ Bg, long bstride,
             float* __restrict__ C, unsigned short* __restrict__ H, int ldc,
             const int* __restrict__ arows_g, int ashift, long aexp,
             const int* __restrict__ crows_g, long cexp,
             const int* __restrict__ cnt, int Mfix, int K,
             int MT, int NTn)
{
  const int nwg = gridDim.x;
  const int lin = (blockIdx.x & 7) * (nwg >> 3) + (blockIdx.x >> 3);
  const int mt = lin % MT;
  const int rest = lin / MT;
  const int nt = rest % NTn;
  const int e = rest / NTn;

  const int M = cnt ? cnt[e] : Mfix;
  if (mt * 128 >= M) return;
  const int n0 = nt * 128;

  const int tid = threadIdx.x;
  const int l = tid & 63;
  const int w = tid >> 6;
  const int wm = w >> 1;        // 0..1
  const int wn = w & 1;         // 0..1
  const int fr = l & 15;
  const int fc = l >> 4;

  const int* arows = arows_g ? arows_g + e * CAP : nullptr;
  const int* crows = crows_g ? crows_g + e * CAP : nullptr;
  const unsigned short* Bexp = Bg + (long)e * bstride;

  __shared__ __align__(16) unsigned short sA[3][128 * BK];
  __shared__ __align__(16) unsigned short sB[3][128 * BK];

  // staging: round j covers rows j*64 + w*16 .. +15; lane l -> row +(l>>2), chunk l&3.
  // pre-swizzle source chunk by dest-row bits {1,3}:
  const int rb_s = ((l >> 3) & 1) | (((l >> 5) & 1) << 1);
  const int sch = ((l & 3) ^ rb_s) * 8;
  long aoff[2], boff[2];
#pragma unroll
  for (int j = 0; j < 2; ++j) {
    const int rloc = j * 64 + w * 16 + (l >> 2);
    int r = mt * 128 + rloc;
    if (r > M - 1) r = M - 1;
    const long arow = arows ? (long)(arows[r] >> ashift) : (aexp * e + r);
    aoff[j] = arow * (long)ldka + sch;
    boff[j] = (long)(n0 + rloc) * K + sch;
  }

  // fragment-read swizzle (per-lane constant): physical chunk = fc ^ bits{1,3}(fr)
  const int rb_r = ((fr >> 1) & 1) | (((fr >> 3) & 1) << 1);
  const int pcoff = (fc ^ rb_r) * 8;

  f32x4 acc[4][4];
#pragma unroll
  for (int i = 0; i < 4; ++i)
#pragma unroll
    for (int j = 0; j < 4; ++j) acc[i][j] = (f32x4)0.f;

  const int NT = K / BK;

  auto stage = [&](int buf, int kt) {
#pragma unroll
    for (int j = 0; j < 2; ++j) {
      gld16(Ag + aoff[j] + kt, &sA[buf][(j * 64 + w * 16) * BK]);
      gld16(Bexp + boff[j] + kt, &sB[buf][(j * 64 + w * 16) * BK]);
    }
  };

  stage(0, 0);
  stage(1, BK);

  int rb = 0, wb = 2;
  for (int t = 0; t < NT; ++t) {
    // stage(t) was issued two iterations ago (4 loads/stage/wave): force it done,
    // allow the newest stage (t+1) to stay in flight.
    if (t + 1 < NT) asm volatile("s_waitcnt vmcnt(4)" ::: "memory");
    else            asm volatile("s_waitcnt vmcnt(0)" ::: "memory");
    __builtin_amdgcn_s_barrier();          // all waves' stage(t) landed; all prior
    __builtin_amdgcn_sched_barrier(0);     // reads of buf[wb] done (pin order)

    if (t + 2 < NT) stage(wb, (t + 2) * BK);

    short8 fa[4], fb[4];
#pragma unroll
    for (int mi = 0; mi < 4; ++mi)
      fa[mi] = *(const short8*)&sA[rb][(wm * 64 + mi * 16 + fr) * BK + pcoff];
#pragma unroll
    for (int ni = 0; ni < 4; ++ni)
      fb[ni] = *(const short8*)&sB[rb][(wn * 64 + ni * 16 + fr) * BK + pcoff];
#pragma unroll
    for (int mi = 0; mi < 4; ++mi)
#pragma unroll
      for (int ni = 0; ni < 4; ++ni)
        acc[mi][ni] = __builtin_amdgcn_mfma_f32_16x16x32_bf16(fa[mi], fb[ni], acc[mi][ni], 0, 0, 0);

    rb = (rb == 2) ? 0 : rb + 1;
    wb = (wb == 2) ? 0 : wb + 1;
  }

  // epilogue: C/D layout col=lane&15, row=(lane>>4)*4+rr
#pragma unroll
  for (int mi = 0; mi < 4; ++mi)
#pragma unroll
    for (int rr = 0; rr < 4; ++rr) {
      const int r = mt * 128 + wm * 64 + mi * 16 + fc * 4 + rr;
      if (r >= M) continue;
      const long crow = crows ? (long)crows[r] : (cexp * e + r);
      if constexpr (EPI == 2) {
#pragma unroll
        for (int np = 0; np < 2; ++np) {
          const float g = acc[mi][2 * np][rr];
          const float u = acc[mi][2 * np + 1][rr];
          const float h = u * (g / (1.f + __expf(-g)));   // silu(g)*u
          const int i = (n0 / 32 + 2 * wn + np) * 16 + fr;  // logical col
          H[crow * (long)ldc + i] = f2bf(h);
        }
      } else {
#pragma unroll
        for (int ni = 0; ni < 4; ++ni) {
          const int col = n0 + wn * 64 + ni * 16 + fr;
          C[crow * (long)ldc + col] = acc[mi][ni][rr];
        }
      }
    }
}

// ------------- combine: out[t] += sum_k w_k * o_slot[t*4+k] -------------
__global__ __launch_bounds__(256) void combine_kernel(
    const float* __restrict__ o_slot, const float* __restrict__ topw,
    float* __restrict__ out)
{
  const int t = blockIdx.x;
  float w[TOPK];
#pragma unroll
  for (int k = 0; k < TOPK; ++k) w[k] = topw[t * TOPK + k];
  float* orow = out + (size_t)t * HIDDEN;
  for (int c = threadIdx.x * 4; c < HIDDEN; c += 256 * 4) {
    float4 acc = *reinterpret_cast<float4*>(orow + c);
#pragma unroll
    for (int k = 0; k < TOPK; ++k) {
      if (w[k] != 0.f) {
        float4 v = ld4f(o_slot + ((size_t)(t * TOPK + k)) * HIDDEN + c);
        acc.x += w[k] * v.x; acc.y += w[k] * v.y;
        acc.z += w[k] * v.z; acc.w += w[k] * v.w;
      }
    }
    *reinterpret_cast<float4*>(orow + c) = acc;
  }
}

extern "C" void kernel_launch(void* const* d_in, const int* in_sizes, int n_in,
                              void* d_out, int out_size, void* d_ws, size_t ws_size,
                              hipStream_t stream)
{
  const float* x   = (const float*)d_in[0];
  const float* wg  = (const float*)d_in[1];
  const float* w1  = (const float*)d_in[2];
  const float* w3  = (const float*)d_in[3];
  const float* w2  = (const float*)d_in[4];
  const float* ws1 = (const float*)d_in[5];
  const float* ws3 = (const float*)d_in[6];
  const float* ws2 = (const float*)d_in[7];
  float* out = (float*)d_out;

  char* w = (char*)d_ws;
  int*   topi   = (int*)w;   w += (size_t)T_TOKENS * TOPK * 4;
  float* topw   = (float*)w; w += (size_t)T_TOKENS * TOPK * 4;
  int*   rowtok = (int*)w;   w += (size_t)NEXP * CAP * 4;
  int*   count  = (int*)w;   w += 256;
  uintptr_t a = (uintptr_t)w; a = (a + 255) & ~(uintptr_t)255; w = (char*)a;

  const size_t XSZ  = (size_t)T_TOKENS * HIDDEN;            // 4.19M
  const size_t WSI  = (size_t)2 * HIDDEN * SINTER;          // 11.5M  (interleaved ws1/ws3)
  const size_t WRI  = (size_t)2 * NEXP * HIDDEN * INTER;    // 92.3M  (interleaved w1/w3)
  const size_t HSSZ = (size_t)T_TOKENS * SINTER;            // 5.77M
  const size_t HRSZ = (size_t)NEXP * CAP * INTER;           // 17.3M

  unsigned short* xb  = (unsigned short*)w; w += XSZ * 2;   // 8.4 MB
  unsigned short* wSi = (unsigned short*)w; w += WSI * 2;   // 23.1 MB; first half reused as ws2T
  unsigned short* wRi = (unsigned short*)w; w += WRI * 2;   // 184.5 MB; reused: w2T (92.3) + o_slot (67.1)
  unsigned short* hs  = (unsigned short*)w; w += HSSZ * 2;  // 11.5 MB
  unsigned short* hr  = (unsigned short*)w; w += HRSZ * 2;  // 34.6 MB
  // aliases into dead regions (stream-ordered reuse):
  unsigned short* wS2 = wSi;                                        // after shared upgate GEMM
  unsigned short* wR2 = wRi;                                        // after routed upgate GEMM
  float* o_slot = (float*)(wRi + (size_t)NEXP * HIDDEN * INTER);    // 67.1 MB, after wR2

  router_kernel<<<T_TOKENS, 64, 0, stream>>>(x, wg, topi, topw);
  partition_kernel<<<1, 1024, 0, stream>>>(topi, topw, rowtok, count);
  cvt_x_kernel<<<(int)(XSZ / (256 * 8)), 256, 0, stream>>>(x, xb);

  // ---- shared upgate: hs = silu(x@ws1) * (x@ws3), fused via interleaved weights ----
  tcvt_w_kernel<<<dim3(HIDDEN / 64, SINTER / 64, 1), 256, 0, stream>>>(
      ws1, wSi, HIDDEN, SINTER, 0L, 2, 0);
  tcvt_w_kernel<<<dim3(HIDDEN / 64, SINTER / 64, 1), 256, 0, stream>>>(
      ws3, wSi, HIDDEN, SINTER, 0L, 2, 1);
  gemm_bf<2><<<(T_TOKENS / 128) * (2 * SINTER / 128), 256, 0, stream>>>(
      xb, HIDDEN, wSi, 0L, nullptr, hs, SINTER,
      nullptr, 0, 0L, nullptr, 0L,
      nullptr, T_TOKENS, HIDDEN, T_TOKENS / 128, 2 * SINTER / 128);

  // ---- routed upgate: hr = silu(gather(x)@w1[e]) * (gather(x)@w3[e]) ----
  tcvt_w_kernel<<<dim3(HIDDEN / 64, INTER / 64, NEXP), 256, 0, stream>>>(
      w1, wRi, HIDDEN, INTER, (long)2 * HIDDEN * INTER, 2, 0);
  tcvt_w_kernel<<<dim3(HIDDEN / 64, INTER / 64, NEXP), 256, 0, stream>>>(
      w3, wRi, HIDDEN, INTER, (long)2 * HIDDEN * INTER, 2, 1);
  gemm_bf<2><<<(CAP / 128) * (2 * INTER / 128) * NEXP, 256, 0, stream>>>(
      xb, HIDDEN, wRi, (long)2 * HIDDEN * INTER, nullptr, hr, INTER,
      rowtok, 2, 0L, nullptr, (long)CAP,
      count, 0, HIDDEN, CAP / 128, 2 * INTER / 128);

  // ---- shared down: out = hs @ ws2 (ws2T overwrites wSi region - dead) ----
  tcvt_w_kernel<<<dim3(SINTER / 64, HIDDEN / 64, 1), 256, 0, stream>>>(
      ws2, wS2, SINTER, HIDDEN, 0L, 1, 0);
  gemm_bf<0><<<(T_TOKENS / 128) * (HIDDEN / 128), 256, 0, stream>>>(
      hs, SINTER, wS2, 0L, out, nullptr, HIDDEN,
      nullptr, 0, 0L, nullptr, 0L,
      nullptr, T_TOKENS, SINTER, T_TOKENS / 128, HIDDEN / 128);

  // ---- routed down: o_slot = hr @ w2[e] (w2T overwrites wRi head - dead) ----
  tcvt_w_kernel<<<dim3(INTER / 64, HIDDEN / 64, NEXP), 256, 0, stream>>>(
      w2, wR2, INTER, HIDDEN, (long)INTER * HIDDEN, 1, 0);
  gemm_bf<0><<<(CAP / 128) * (HIDDEN / 128) * NEXP, 256, 0, stream>>>(
      hr, INTER, wR2, (long)INTER * HIDDEN, o_slot, nullptr, HIDDEN,
      nullptr, 0, (long)CAP, rowtok, 0L,
      count, 0, INTER, CAP / 128, HIDDEN / 128);

  combine_kernel<<<T_TOKENS, 256, 0, stream>>>(o_slot, topw, out);
}